// Round 4
// baseline (304.799 us; speedup 1.0000x reference)
//
#include <hip/hip_runtime.h>

#define BS   8192
#define DIM  1024
#define TINV 10.0f    // 1 / TEMPERATURE
#define MARGIN 1.0f   // max(0.01, 1.0 - 0.1*0.0)

#define BM  128
#define BN  128
#define BKB 128       // fp8 K-bytes per staging iteration (16x16x128 MFMA)

// fp8 values are the normalized elements scaled by 16 -> dot = 256 * cos
#define QSCALE   16.0f
#define INV_QSQ  (1.0f / 256.0f)

typedef __attribute__((ext_vector_type(4))) float f32x4;
typedef __attribute__((ext_vector_type(4))) int   int4v;
typedef __attribute__((ext_vector_type(8))) int   int8v;

// ---------------- Kernel 1: L2-normalize rows, emit fp8(e4m3,x16) + posdist -
// (unchanged — one wave per row, pure shfl reduction)
__global__ __launch_bounds__(256) void normalize_kernel(
    const float* __restrict__ feat,
    unsigned char* __restrict__ Afp8,
    unsigned char* __restrict__ Nfp8,
    float* __restrict__ posdist)
{
    const int lane = threadIdx.x & 63;
    const int row  = blockIdx.x * 4 + (threadIdx.x >> 6);   // wave = row

    const float4* fo = (const float4*)(feat + (size_t)row * DIM);
    const float4* fp = (const float4*)(feat + (size_t)(BS + row) * DIM);
    const float4* fn = (const float4*)(feat + (size_t)(2 * BS + row) * DIM);

    float4 o[4], p[4], n[4];
    #pragma unroll
    for (int k = 0; k < 4; k++) {
        o[k] = fo[lane + 64 * k];
        p[k] = fp[lane + 64 * k];
        n[k] = fn[lane + 64 * k];
    }

    float so = 0.f, sp = 0.f, sn = 0.f;
    #pragma unroll
    for (int k = 0; k < 4; k++) {
        so += o[k].x*o[k].x + o[k].y*o[k].y + o[k].z*o[k].z + o[k].w*o[k].w;
        sp += p[k].x*p[k].x + p[k].y*p[k].y + p[k].z*p[k].z + p[k].w*p[k].w;
        sn += n[k].x*n[k].x + n[k].y*n[k].y + n[k].z*n[k].z + n[k].w*n[k].w;
    }
    #pragma unroll
    for (int off = 1; off < 64; off <<= 1) {
        so += __shfl_xor(so, off);
        sp += __shfl_xor(sp, off);
        sn += __shfl_xor(sn, off);
    }

    const float io  = 1.0f / fmaxf(sqrtf(so), 1e-12f);
    const float ip  = 1.0f / fmaxf(sqrtf(sp), 1e-12f);
    const float in_ = 1.0f / fmaxf(sqrtf(sn), 1e-12f);

    int* Ar = (int*)(Afp8 + (size_t)row * DIM);
    int* Nr = (int*)(Nfp8 + (size_t)row * DIM);

    float d = 0.f;
    #pragma unroll
    for (int k = 0; k < 4; k++) {
        float ax = o[k].x*io, ay = o[k].y*io, az = o[k].z*io, aw = o[k].w*io;
        float nx = n[k].x*in_, ny = n[k].y*in_, nz = n[k].z*in_, nw = n[k].w*in_;
        int pa = __builtin_amdgcn_cvt_pk_fp8_f32(ax*QSCALE, ay*QSCALE, 0, false);
        pa     = __builtin_amdgcn_cvt_pk_fp8_f32(az*QSCALE, aw*QSCALE, pa, true);
        int pn = __builtin_amdgcn_cvt_pk_fp8_f32(nx*QSCALE, ny*QSCALE, 0, false);
        pn     = __builtin_amdgcn_cvt_pk_fp8_f32(nz*QSCALE, nw*QSCALE, pn, true);
        Ar[lane + 64 * k] = pa;      // coalesced 4B stores
        Nr[lane + 64 * k] = pn;
        float dx = ax - p[k].x*ip, dy = ay - p[k].y*ip;
        float dz = az - p[k].z*ip, dw = aw - p[k].w*ip;
        d += dx*dx + dy*dy + dz*dz + dw*dw;
    }
    #pragma unroll
    for (int off = 1; off < 64; off <<= 1) d += __shfl_xor(d, off);
    if (lane == 0) posdist[row] = d * TINV;
}

// Load one 32B fragment from swizzled LDS: lo chunk at `off`, hi at off^16
// (chunk parity: (q2+1)^x == (q2^x)^1 for even q2). Union avoids repack.
__device__ __forceinline__ int8v ld_frag(const unsigned char* __restrict__ p,
                                         int off) {
    union { int8v v; struct { int4v lo, hi; } s; } u;
    u.s.lo = *(const int4v*)(p + off);
    u.s.hi = *(const int4v*)(p + (off ^ 16));
    return u.v;
}

// ---------------- Kernel 2: MX-fp8 16x16x128 MFMA max-GEMM (R13/R14) --------
// R13 resubmit (R13 bench died infra-side: "container failed twice";
// kernel re-audited — staging coverage, swizzle involution, epilogue
// ownership, ws bounds all check out).
// R13: 64x64 wave tile (4x4 frags, 16 mfma), block 128x128, 2x2 waves,
// single-buffered LDS (32 KB), R9's proven 2-barrier structure.
// R12 post-mortem: explicit dbuf was NEUTRAL (110 us == R9's 108) — the
// barrier's vmcnt(0) drain + 3-blocks/CU implicit overlap already covered
// it (matches guide m99/m100). Counter arithmetic shows the real limit:
// 12.3K b128/CU x ~16 cyc = 197K cyc vs 264K kernel cyc -> LDS read pipe
// ~75% busy; MFMA only 71K cyc (25% = MfmaUtil). Fix = fewer LDS bytes
// per FLOP: 64x64 wave tile gives 64 FLOP/B (was 43.7), keeping 16x16x128
// shape + small f32x4 accs (R11's 32x32 fat-acc VGPR blowup avoided).
// Bank-conflict floor: 4.0 cyc/b128 in R9+R11 both -> structural, ignore.
__global__ __launch_bounds__(256) void maxgemm_kernel(
    const unsigned char* __restrict__ Afp8,
    const unsigned char* __restrict__ Nfp8,
    float* __restrict__ partial)   // [BS][128] row-major
{
    __shared__ unsigned char As[BM * BKB];   // 16 KiB
    __shared__ unsigned char Bs[BN * BKB];   // 16 KiB

    const int tid  = threadIdx.x;
    const int lane = tid & 63;
    const int w    = tid >> 6;      // wave 0..3
    const int wr   = w >> 1;        // wave-row: owns 64 output rows
    const int wc   = w & 1;         // wave-col: owns 64 output cols
    const int rowBase = blockIdx.y * BM;
    const int colBase = blockIdx.x * BN;

    const int lrow = lane >> 3;                      // 0..7: row in 8-row slab
    const int gcol = ((lane & 7) ^ lrow) * 16;       // swizzled 16B chunk (bytes)

    const unsigned char* Ag = Afp8 + (size_t)rowBase * DIM;
    const unsigned char* Bg = Nfp8 + (size_t)colBase * DIM;

    const int q2   = (lane >> 4) * 2;                // first 16B chunk of quad
    const int arow = wr * 64 + (lane & 15);          // + i*16, i=0..3
    const int brow = wc * 64 + (lane & 15);          // + j*16, j=0..3
    const int aoff = arow * BKB + ((q2 ^ (arow & 7)) << 4);
    const int boff = brow * BKB + ((q2 ^ (brow & 7)) << 4);

    f32x4 acc[4][4];
    #pragma unroll
    for (int i = 0; i < 4; i++)
        #pragma unroll
        for (int j = 0; j < 4; j++)
            acc[i][j] = (f32x4){0.f, 0.f, 0.f, 0.f};

    for (int k0 = 0; k0 < DIM; k0 += BKB) {
        __syncthreads();  // prior iter's LDS reads done
        #pragma unroll
        for (int c = 0; c < 4; c++) {               // A: 4 slabs of 8 rows/wave
            const int r0 = w * 32 + c * 8;
            __builtin_amdgcn_global_load_lds(
                (const __attribute__((address_space(1))) void*)
                    (Ag + (size_t)(r0 + lrow) * DIM + k0 + gcol),
                (__attribute__((address_space(3))) void*)(As + r0 * BKB),
                16, 0, 0);
        }
        #pragma unroll
        for (int c = 0; c < 4; c++) {               // B: 4 slabs of 8 rows/wave
            const int r0 = w * 32 + c * 8;
            __builtin_amdgcn_global_load_lds(
                (const __attribute__((address_space(1))) void*)
                    (Bg + (size_t)(r0 + lrow) * DIM + k0 + gcol),
                (__attribute__((address_space(3))) void*)(Bs + r0 * BKB),
                16, 0, 0);
        }
        __syncthreads();  // vmcnt drained by barrier semantics

        int8v bf[4];
        #pragma unroll
        for (int j = 0; j < 4; j++)
            bf[j] = ld_frag(Bs, boff + j * 16 * BKB);

        #pragma unroll
        for (int i = 0; i < 4; i++) {
            const int8v a = ld_frag(As, aoff + i * 16 * BKB);
            #pragma unroll
            for (int j = 0; j < 4; j++)
                acc[i][j] = __builtin_amdgcn_mfma_scale_f32_16x16x128_f8f6f4(
                    a, bf[j], acc[i][j],
                    0, 0,               // cbsz=FP8(e4m3), blgp=FP8(e4m3)
                    0, 0x7F7F7F7F,      // opselA, scaleA = 1.0
                    0, 0x7F7F7F7F);     // opselB, scaleB = 1.0
        }
    }

    // Epilogue: per-row max over this wave's 64 columns.
    // C/D layout (m89/m91): col = lane&15, row = (lane>>4)*4 + reg.
    const int stripe = blockIdx.x * 2 + wc;          // 64-col stripe index
    #pragma unroll
    for (int i = 0; i < 4; i++) {
        #pragma unroll
        for (int r = 0; r < 4; r++) {
            float v = fmaxf(fmaxf(acc[i][0][r], acc[i][1][r]),
                            fmaxf(acc[i][2][r], acc[i][3][r]));
            v = fmaxf(v, __shfl_xor(v, 1));
            v = fmaxf(v, __shfl_xor(v, 2));
            v = fmaxf(v, __shfl_xor(v, 4));
            v = fmaxf(v, __shfl_xor(v, 8));
            if ((lane & 15) == 0) {
                const int row = rowBase + wr * 64 + i * 16 + (lane >> 4) * 4 + r;
                partial[(size_t)row * 128 + stripe] = v;   // = 256 * cos
            }
        }
    }
}

// ---------------- Kernel 3: stripe-max -> loss terms -> per-block partials --
// grid 64 -> 256 blocks (was 1 wave/CU active work, pure latency exposure).
__global__ __launch_bounds__(256) void reduce_kernel(
    const float* __restrict__ partial,
    const float* __restrict__ posdist,
    float* __restrict__ blockpart)   // [256][3]
{
    const int tid  = threadIdx.x;
    const int lane = tid & 63;
    const int w    = tid >> 6;
    __shared__ float red[4][3];

    float sloss = 0.f, spos = 0.f, shard = 0.f;

    #pragma unroll
    for (int i = 0; i < 8; i++) {
        const int row = blockIdx.x * 32 + w * 8 + i;
        float v = fmaxf(partial[(size_t)row * 128 + lane],
                        partial[(size_t)row * 128 + 64 + lane]);
        #pragma unroll
        for (int off = 1; off < 64; off <<= 1) v = fmaxf(v, __shfl_xor(v, off));
        if (lane == 0) {
            // v = 256*cos  ->  hard = (2 - 2*cos)/T = (2 - v/128)*TINV
            const float hard = (2.0f - 2.0f * v * INV_QSQ) * TINV;
            const float pos  = posdist[row];
            sloss += fmaxf(MARGIN + pos - hard, 0.0f);
            spos  += pos;
            shard += hard;
        }
    }
    if (lane == 0) { red[w][0] = sloss; red[w][1] = spos; red[w][2] = shard; }
    __syncthreads();
    if (tid == 0) {
        #pragma unroll
        for (int k = 0; k < 3; k++)
            blockpart[blockIdx.x * 3 + k] =
                red[0][k] + red[1][k] + red[2][k] + red[3][k];
    }
}

// ---------------- Kernel 4: finalize means (one wave, no atomics) -----------
__global__ __launch_bounds__(64) void finalize_kernel(
    const float* __restrict__ blockpart,
    float* __restrict__ out)
{
    const int lane = threadIdx.x;
    float a = 0.f, b = 0.f, c = 0.f;
    #pragma unroll
    for (int m = 0; m < 4; m++) {
        a += blockpart[(lane + 64 * m) * 3 + 0];
        b += blockpart[(lane + 64 * m) * 3 + 1];
        c += blockpart[(lane + 64 * m) * 3 + 2];
    }
    #pragma unroll
    for (int off = 1; off < 64; off <<= 1) {
        a += __shfl_xor(a, off);
        b += __shfl_xor(b, off);
        c += __shfl_xor(c, off);
    }
    if (lane == 0) {
        const float inv = 1.0f / (float)BS;
        out[0] = a * inv;
        out[1] = b * inv;
        out[2] = c * inv;
    }
}

extern "C" void kernel_launch(void* const* d_in, const int* in_sizes, int n_in,
                              void* d_out, int out_size, void* d_ws, size_t ws_size,
                              hipStream_t stream) {
    const float* feat = (const float*)d_in[0];
    char* ws = (char*)d_ws;

    // ws layout: Afp8 8MiB | Nfp8 8MiB | partial 4MiB | posdist 32KiB | blockpart
    unsigned char* Afp8      = (unsigned char*)ws;
    unsigned char* Nfp8      = (unsigned char*)(ws + ((size_t)8 << 20));
    float*         partial   = (float*)(ws + ((size_t)16 << 20));
    float*         posdist   = (float*)(ws + ((size_t)20 << 20));
    float*         blockpart = (float*)(ws + ((size_t)20 << 20) + 32768);

    normalize_kernel<<<BS / 4, 256, 0, stream>>>(feat, Afp8, Nfp8, posdist);

    maxgemm_kernel<<<dim3(BS / BN, BS / BM), 256, 0, stream>>>(Afp8, Nfp8, partial);

    reduce_kernel<<<256, 256, 0, stream>>>(partial, posdist, blockpart);
    finalize_kernel<<<1, 64, 0, stream>>>(blockpart, (float*)d_out);
}